// Round 6
// baseline (984.801 us; speedup 1.0000x reference)
//
#include <hip/hip_runtime.h>
#include <math.h>

#define NN 100000
#define NE 1600000
#define CC 128
#define C3 384
#define SCAN_B 256
#define SCAN_NB ((NN + SCAN_B - 1) / SCAN_B)  // 391

typedef __attribute__((ext_vector_type(4))) float f4;
typedef __attribute__((ext_vector_type(8))) short s8;

__device__ __forceinline__ float sigmoidf_(float x) { return 1.0f / (1.0f + __expf(-x)); }
__device__ __forceinline__ float tanhf_(float x) { return 2.0f / (1.0f + __expf(-2.0f * x)) - 1.0f; }

__device__ __forceinline__ short f2bf(float x) {
    unsigned u = __float_as_uint(x);
    unsigned r = (u + 0x7fffu + ((u >> 16) & 1u)) >> 16;
    return (short)r;
}
__device__ __forceinline__ float bf2f(short s) {
    return __uint_as_float(((unsigned)(unsigned short)s) << 16);
}

// ---- edge dtype detection: int64 => every odd int32 word is a zero high-word ----
__global__ void k_detect(const int* __restrict__ edges, int* __restrict__ flag) {
    if (threadIdx.x == 0) {
        int allz = 1;
        for (int i = 0; i < 32; i++)
            if (edges[2 * i + 1] != 0) allz = 0;
        *flag = allz;  // 1 => int64 layout
    }
}

__device__ __forceinline__ int edge_val(const void* edges, int f, long long idx) {
    return f ? (int)((const long long*)edges)[idx] : ((const int*)edges)[idx];
}

__global__ void k_count(const void* __restrict__ edges, const int* __restrict__ flag,
                        int* __restrict__ counts) {
    int e = blockIdx.x * blockDim.x + threadIdx.x;
    if (e < NE) {
        int f = *flag;
        int d = edge_val(edges, f, (long long)NE + e);
        atomicAdd(&counts[d], 1);
    }
}

// ---- multi-block scan ----
__global__ void k_scan1(const int* __restrict__ counts, int* __restrict__ bsum) {
    __shared__ int red[4];
    int t = threadIdx.x;
    int i = blockIdx.x * SCAN_B + t;
    int v = (i < NN) ? counts[i] : 0;
#pragma unroll
    for (int off = 32; off; off >>= 1) v += __shfl_down(v, off);
    if ((t & 63) == 0) red[t >> 6] = v;
    __syncthreads();
    if (t == 0) bsum[blockIdx.x] = red[0] + red[1] + red[2] + red[3];
}

__global__ void k_scan2(const int* __restrict__ bsum, int* __restrict__ boff) {
    __shared__ int lds[512];
    int t = threadIdx.x;
    int v = (t < SCAN_NB) ? bsum[t] : 0;
    lds[t] = v;
    __syncthreads();
    for (int off = 1; off < 512; off <<= 1) {
        int u = (t >= off) ? lds[t - off] : 0;
        __syncthreads();
        lds[t] += u;
        __syncthreads();
    }
    if (t < SCAN_NB) boff[t] = lds[t] - v;  // exclusive
}

__global__ void k_scan3(const int* __restrict__ counts, const int* __restrict__ boff,
                        int* __restrict__ rowptr, float* __restrict__ inv_denom) {
    __shared__ int lds[SCAN_B];
    int t = threadIdx.x;
    int i = blockIdx.x * SCAN_B + t;
    int v = (i < NN) ? counts[i] : 0;
    lds[t] = v;
    __syncthreads();
    for (int off = 1; off < SCAN_B; off <<= 1) {
        int u = (t >= off) ? lds[t - off] : 0;
        __syncthreads();
        lds[t] += u;
        __syncthreads();
    }
    if (i < NN) {
        rowptr[i] = boff[blockIdx.x] + lds[t] - v;
        inv_denom[i] = 1.0f / (float)((v > 1) ? v : 1);
    }
    if (i == 0) rowptr[NN] = NE;
}

__global__ void k_bucket(const void* __restrict__ edges, const int* __restrict__ flag,
                         const int* __restrict__ rowptr, int* __restrict__ cursor,
                         int* __restrict__ csr_src) {
    int e = blockIdx.x * blockDim.x + threadIdx.x;
    if (e < NE) {
        int f = *flag;
        int s = edge_val(edges, f, e);
        int d = edge_val(edges, f, (long long)NE + e);
        int pos = atomicAdd(&cursor[d], 1);
        csr_src[rowptr[d] + pos] = s;
    }
}

// ---- weight prep (validated R2) ----
__global__ void k_prep(const float* __restrict__ weight, const float* __restrict__ w_ih,
                       const float* __restrict__ w_hh, const float* __restrict__ b_ih,
                       const float* __restrict__ b_hh,
                       short* __restrict__ B1hi, short* __restrict__ B1lo,
                       short* __restrict__ B2hi, short* __restrict__ B2lo,
                       float* __restrict__ bvec) {
    const int P1 = 3 * C3 * CC;
    int gid = blockIdx.x * blockDim.x + threadIdx.x;
    if (gid < P1) {
        int i = gid / (C3 * CC);
        int rem = gid % (C3 * CC);
        int j = rem / CC;
        int k = rem % CC;
        const float* Wr = weight + i * CC * CC + k * CC;
        const float* ir = w_ih + j * CC;
        float v = 0.f;
#pragma unroll 4
        for (int c = 0; c < CC; c++) v += Wr[c] * ir[c];
        short hi = f2bf(v);
        short lo = f2bf(v - bf2f(hi));
        if (j < 256) {
            int idx = i * 65536 + j * 256 + k;
            B1hi[idx] = hi; B1lo[idx] = lo;
        } else {
            int idx = i * 32768 + (j - 256) * 128 + k;
            B2hi[idx] = hi; B2lo[idx] = lo;
        }
    } else if (gid < 2 * P1) {
        int g = gid - P1;
        int i = g / (C3 * CC);
        int rem = g % (C3 * CC);
        int j = rem / CC;
        int k = rem % CC;
        float v = w_hh[j * CC + k];
        short hi = f2bf(v);
        short lo = f2bf(v - bf2f(hi));
        if (j < 256) {
            int idx = i * 65536 + j * 256 + 128 + k;
            B1hi[idx] = hi; B1lo[idx] = lo;
        } else {
            int idx = i * 32768 + (j - 256 + 128) * 128 + k;
            B2hi[idx] = hi; B2lo[idx] = lo;
        }
    } else if (gid < 2 * P1 + 512) {
        int j = gid - 2 * P1;
        float v;
        if (j < 256) v = b_ih[j] + b_hh[j];
        else if (j < 384) v = b_ih[j];
        else v = b_hh[j - 128];
        bvec[j] = v;
    }
}

// ---- x -> split-bf16 (hhi/hlo) ----
__global__ void k_cvt(const float* __restrict__ x, unsigned short* __restrict__ hhi,
                      unsigned short* __restrict__ hlo) {
    long long i = ((long long)blockIdx.x * 256 + threadIdx.x) * 8;
    float4 v0 = *(const float4*)(x + i);
    float4 v1 = *(const float4*)(x + i + 4);
    float f[8] = {v0.x, v0.y, v0.z, v0.w, v1.x, v1.y, v1.z, v1.w};
    s8 oh, ol;
#pragma unroll
    for (int q = 0; q < 8; q++) {
        short hi = f2bf(f[q]);
        oh[q] = hi;
        ol[q] = f2bf(f[q] - bf2f(hi));
    }
    *(s8*)(hhi + i) = oh;
    *(s8*)(hlo + i) = ol;
}

// ---- aggregation: bf16 (hhi) gather, fp32 accumulate ----
// One wave per node; half-wave (32 lanes x 8 B) reads one full bf16 row per edge.
__global__ void k_agg(const unsigned short* __restrict__ hhi, const int* __restrict__ rowptr,
                      const int* __restrict__ csr_src, const float* __restrict__ inv_denom,
                      float* __restrict__ a_hat) {
    int wid = (blockIdx.x * blockDim.x + threadIdx.x) >> 6;
    int lane = threadIdx.x & 63;
    if (wid >= NN) return;
    int lo = rowptr[wid], hi = rowptr[wid + 1];
    int half = lane >> 5;
    int l32 = lane & 31;
    float a0 = 0.f, a1 = 0.f, a2 = 0.f, a3 = 0.f;
    for (int e = lo + half; e < hi; e += 2) {
        int s = csr_src[e];
        ushort4 v = ((const ushort4*)(hhi + (long long)s * CC))[l32];
        a0 += bf2f((short)v.x);
        a1 += bf2f((short)v.y);
        a2 += bf2f((short)v.z);
        a3 += bf2f((short)v.w);
    }
    a0 += __shfl_down(a0, 32);
    a1 += __shfl_down(a1, 32);
    a2 += __shfl_down(a2, 32);
    a3 += __shfl_down(a3, 32);
    if (half == 0) {
        float inv = inv_denom[wid];
        float4 r;
        r.x = a0 * inv; r.y = a1 * inv; r.z = a2 * inv; r.w = a3 * inv;
        ((float4*)(a_hat + (long long)wid * CC))[l32] = r;
    }
}

// ---- fused split-bf16 MFMA GEMM + GRU; h stored ONLY as hhi/hlo, updated IN PLACE ----
// Safe: each block reads exactly the 64 h-rows it writes, staged to LDS before any store.
__global__ __launch_bounds__(256, 2) void k_gru_mfma(
    const float* __restrict__ a_hat,
    unsigned short* __restrict__ hhi, unsigned short* __restrict__ hlo,
    const short* __restrict__ B1hi, const short* __restrict__ B1lo,
    const short* __restrict__ B2hi, const short* __restrict__ B2lo,
    const float* __restrict__ bvec) {
    __shared__ short Ahi[16384];
    __shared__ short Alo[16384];
    int t = threadIdx.x;
    long long nb = (long long)blockIdx.x * 64;

    // stage A = [split(a_hat) | hhi/hlo]: 64 rows x 32 chunks of 8 elems
#pragma unroll
    for (int i = 0; i < 8; i++) {
        int ci = t + 256 * i;
        int rr = ci >> 5;
        int c = ci & 31;
        long long row = nb + rr;
        if (row >= NN) row = NN - 1;
        int off = (c >> 2) * 2048 + (rr >> 4) * 512 + (rr & 15) * 32 + (c & 3) * 8;
        if (c < 16) {
            const float* rp = a_hat + row * CC + c * 8;
            float4 v0 = *(const float4*)rp;
            float4 v1 = *(const float4*)(rp + 4);
            float f[8] = {v0.x, v0.y, v0.z, v0.w, v1.x, v1.y, v1.z, v1.w};
            s8 vh, vl;
#pragma unroll
            for (int q = 0; q < 8; q++) {
                short hi = f2bf(f[q]);
                vh[q] = hi;
                vl[q] = f2bf(f[q] - bf2f(hi));
            }
            *(s8*)&Ahi[off] = vh;
            *(s8*)&Alo[off] = vl;
        } else {
            long long src = row * CC + (c - 16) * 8;
            *(s8*)&Ahi[off] = *(const s8*)(hhi + src);
            *(s8*)&Alo[off] = *(const s8*)(hlo + src);
        }
    }
    __syncthreads();

    int wv = t >> 6;
    int lane = t & 63;
    int lm = lane & 15;
    int lq = lane >> 4;
    int g0 = 2 * wv;

    f4 aR[2][4], aZ[2][4], aN[2][4], aH[2][4];
#pragma unroll
    for (int gp = 0; gp < 2; gp++) {
        int j = (g0 + gp) * 16 + lm;
        float bR = bvec[j], bZ = bvec[128 + j], bN = bvec[256 + j], bH = bvec[384 + j];
#pragma unroll
        for (int ch = 0; ch < 4; ch++) {
            aR[gp][ch] = (f4){bR, bR, bR, bR};
            aZ[gp][ch] = (f4){bZ, bZ, bZ, bZ};
            aN[gp][ch] = (f4){bN, bN, bN, bN};
            aH[gp][ch] = (f4){bH, bH, bH, bH};
        }
    }

#pragma unroll
    for (int ks = 0; ks < 8; ks++) {
        s8 bRh[2], bRl[2], bZh[2], bZl[2], bGh[2], bGl[2];
#pragma unroll
        for (int gp = 0; gp < 2; gp++) {
            int rowR = (g0 + gp) * 16 + lm;
            int o1 = ks * 32 + lq * 8;
            bRh[gp] = *(const s8*)(B1hi + rowR * 256 + o1);
            bRl[gp] = *(const s8*)(B1lo + rowR * 256 + o1);
            bZh[gp] = *(const s8*)(B1hi + (128 + rowR) * 256 + o1);
            bZl[gp] = *(const s8*)(B1lo + (128 + rowR) * 256 + o1);
            int rowG = (ks < 4) ? rowR : (128 + rowR);
            int o2 = ((ks < 4) ? ks * 32 : (ks - 4) * 32) + lq * 8;
            bGh[gp] = *(const s8*)(B2hi + rowG * 128 + o2);
            bGl[gp] = *(const s8*)(B2lo + rowG * 128 + o2);
        }
#pragma unroll
        for (int ch = 0; ch < 4; ch++) {
            int aoff = ks * 2048 + ch * 512 + lm * 32 + lq * 8;
            s8 ah = *(const s8*)&Ahi[aoff];
            s8 al = *(const s8*)&Alo[aoff];
#pragma unroll
            for (int gp = 0; gp < 2; gp++) {
                aR[gp][ch] = __builtin_amdgcn_mfma_f32_16x16x32_bf16(ah, bRh[gp], aR[gp][ch], 0, 0, 0);
                aR[gp][ch] = __builtin_amdgcn_mfma_f32_16x16x32_bf16(al, bRh[gp], aR[gp][ch], 0, 0, 0);
                aR[gp][ch] = __builtin_amdgcn_mfma_f32_16x16x32_bf16(ah, bRl[gp], aR[gp][ch], 0, 0, 0);
                aZ[gp][ch] = __builtin_amdgcn_mfma_f32_16x16x32_bf16(ah, bZh[gp], aZ[gp][ch], 0, 0, 0);
                aZ[gp][ch] = __builtin_amdgcn_mfma_f32_16x16x32_bf16(al, bZh[gp], aZ[gp][ch], 0, 0, 0);
                aZ[gp][ch] = __builtin_amdgcn_mfma_f32_16x16x32_bf16(ah, bZl[gp], aZ[gp][ch], 0, 0, 0);
                if (ks < 4) {
                    aN[gp][ch] = __builtin_amdgcn_mfma_f32_16x16x32_bf16(ah, bGh[gp], aN[gp][ch], 0, 0, 0);
                    aN[gp][ch] = __builtin_amdgcn_mfma_f32_16x16x32_bf16(al, bGh[gp], aN[gp][ch], 0, 0, 0);
                    aN[gp][ch] = __builtin_amdgcn_mfma_f32_16x16x32_bf16(ah, bGl[gp], aN[gp][ch], 0, 0, 0);
                } else {
                    aH[gp][ch] = __builtin_amdgcn_mfma_f32_16x16x32_bf16(ah, bGh[gp], aH[gp][ch], 0, 0, 0);
                    aH[gp][ch] = __builtin_amdgcn_mfma_f32_16x16x32_bf16(al, bGh[gp], aH[gp][ch], 0, 0, 0);
                    aH[gp][ch] = __builtin_amdgcn_mfma_f32_16x16x32_bf16(ah, bGl[gp], aH[gp][ch], 0, 0, 0);
                }
            }
        }
    }

    // register-only GRU epilogue; write h back in place as hi/lo
#pragma unroll
    for (int gp = 0; gp < 2; gp++) {
        int j = (g0 + gp) * 16 + lm;
        int c = 16 + (j >> 3);
        int obase = (c >> 2) * 2048 + (c & 3) * 8 + (j & 7);
#pragma unroll
        for (int ch = 0; ch < 4; ch++) {
#pragma unroll
            for (int r = 0; r < 4; r++) {
                int node = ch * 16 + lq * 4 + r;
                long long gnode = nb + node;
                int off = obase + ch * 512 + (node & 15) * 32;
                float hp = bf2f(Ahi[off]) + bf2f(Alo[off]);
                float sr = aR[gp][ch][r];
                float sz = aZ[gp][ch][r];
                float in_ = aN[gp][ch][r];
                float hn = aH[gp][ch][r];
                float rg = sigmoidf_(sr);
                float zg = sigmoidf_(sz);
                float nv = tanhf_(in_ + rg * hn);
                float val = (1.f - zg) * nv + zg * hp;
                if (gnode < NN) {
                    short vh = f2bf(val);
                    hhi[gnode * CC + j] = (unsigned short)vh;
                    hlo[gnode * CC + j] = (unsigned short)f2bf(val - bf2f(vh));
                }
            }
        }
    }
}

// ---- out[n] = tanh(mean_c (hhi+hlo)) ----
__global__ void k_out(const unsigned short* __restrict__ hhi,
                      const unsigned short* __restrict__ hlo, float* __restrict__ out) {
    int wid = (blockIdx.x * blockDim.x + threadIdx.x) >> 6;
    int lane = threadIdx.x & 63;
    if (wid >= NN) return;
    ushort2 vh = ((const ushort2*)(hhi + (long long)wid * CC))[lane];
    ushort2 vl = ((const ushort2*)(hlo + (long long)wid * CC))[lane];
    float s = bf2f((short)vh.x) + bf2f((short)vl.x) + bf2f((short)vh.y) + bf2f((short)vl.y);
    for (int off = 32; off; off >>= 1) s += __shfl_down(s, off);
    if (lane == 0) out[wid] = tanhf_(s * (1.0f / 128.0f));
}

extern "C" void kernel_launch(void* const* d_in, const int* in_sizes, int n_in,
                              void* d_out, int out_size, void* d_ws, size_t ws_size,
                              hipStream_t stream) {
    const float* x = (const float*)d_in[0];
    const void* edges = d_in[1];
    const float* weight = (const float*)d_in[2];
    const float* w_ih = (const float*)d_in[3];
    const float* w_hh = (const float*)d_in[4];
    const float* b_ih = (const float*)d_in[5];
    const float* b_hh = (const float*)d_in[6];
    float* out = (float*)d_out;

    char* ws = (char*)d_ws;
    size_t off = 0;
    auto alloc = [&](size_t bytes) -> char* {
        char* p = ws + off;
        off += (bytes + 255) & ~(size_t)255;
        return p;
    };
    // total ws usage ~111.6 MB (R4's proven-safe watermark was 162.8 MB; R5's
    // 188.4 MB overflowed ws_size and corrupted harness memory)
    int* flag = (int*)alloc(4);
    int* counts = (int*)alloc((size_t)NN * 4);
    int* cursor = (int*)alloc((size_t)NN * 4);
    int* rowptr = (int*)alloc((size_t)(NN + 1) * 4);
    int* csr_src = (int*)alloc((size_t)NE * 4);
    float* inv_den = (float*)alloc((size_t)NN * 4);
    int* bsum = (int*)alloc((size_t)SCAN_NB * 4);
    int* boff = (int*)alloc((size_t)SCAN_NB * 4);
    short* B1hi = (short*)alloc((size_t)3 * 65536 * 2);
    short* B1lo = (short*)alloc((size_t)3 * 65536 * 2);
    short* B2hi = (short*)alloc((size_t)3 * 32768 * 2);
    short* B2lo = (short*)alloc((size_t)3 * 32768 * 2);
    float* bvec = (float*)alloc(512 * 4);
    float* a_hat = (float*)alloc((size_t)NN * CC * 4);
    unsigned short* hhi = (unsigned short*)alloc((size_t)NN * CC * 2);
    unsigned short* hlo = (unsigned short*)alloc((size_t)NN * CC * 2);

    hipMemsetAsync(counts, 0, (size_t)NN * 4, stream);
    hipMemsetAsync(cursor, 0, (size_t)NN * 4, stream);

    k_detect<<<1, 64, 0, stream>>>((const int*)edges, flag);
    k_count<<<(NE + 255) / 256, 256, 0, stream>>>(edges, flag, counts);
    k_scan1<<<SCAN_NB, SCAN_B, 0, stream>>>(counts, bsum);
    k_scan2<<<1, 512, 0, stream>>>(bsum, boff);
    k_scan3<<<SCAN_NB, SCAN_B, 0, stream>>>(counts, boff, rowptr, inv_den);
    k_bucket<<<(NE + 255) / 256, 256, 0, stream>>>(edges, flag, rowptr, cursor, csr_src);
    int prep_threads = 2 * 3 * C3 * CC + 512;
    k_prep<<<(prep_threads + 255) / 256, 256, 0, stream>>>(weight, w_ih, w_hh, b_ih, b_hh,
                                                           B1hi, B1lo, B2hi, B2lo, bvec);
    k_cvt<<<(NN * CC) / 2048, 256, 0, stream>>>(x, hhi, hlo);

    const int gru_blocks = (NN + 63) / 64;  // 1563
    for (int i = 0; i < 3; i++) {
        k_agg<<<25000, 256, 0, stream>>>(hhi, rowptr, csr_src, inv_den, a_hat);
        k_gru_mfma<<<gru_blocks, 256, 0, stream>>>(a_hat, hhi, hlo,
                                                   B1hi + (size_t)i * 65536, B1lo + (size_t)i * 65536,
                                                   B2hi + (size_t)i * 32768, B2lo + (size_t)i * 32768,
                                                   bvec);
    }
    k_out<<<25000, 256, 0, stream>>>(hhi, hlo, out);
}